// Round 9
// baseline (148.060 us; speedup 1.0000x reference)
//
#include <hip/hip_runtime.h>
#include <cstddef>

#define BH 4
#define CH 64
#define OH 64
#define HH 128
#define WW 128
#define KK 9
#define HW (HH * WW)     // 16384

typedef __attribute__((ext_vector_type(8))) short short8;       // 8 bf16
typedef __attribute__((ext_vector_type(4))) float f32x4;        // MFMA acc
typedef __attribute__((ext_vector_type(2))) float f32x2;
typedef __attribute__((ext_vector_type(4))) unsigned int uint4v;
typedef __attribute__((ext_vector_type(4))) unsigned short ushort4v;

__device__ __forceinline__ unsigned short f2bf(float f) {
    unsigned u = __float_as_uint(f);
    u += 0x7fffu + ((u >> 16) & 1u);   // RNE
    return (unsigned short)(u >> 16);
}
__device__ __forceinline__ f32x2 bf2x2(unsigned d) {
    f32x2 r;
    r.x = __uint_as_float(d << 16);
    r.y = __uint_as_float(d & 0xffff0000u);
    return r;
}
__device__ __forceinline__ unsigned pack_bf2(f32x2 v) {
    unsigned u0 = __float_as_uint(v.x);
    u0 += 0x7fffu + ((u0 >> 16) & 1u);
    unsigned u1 = __float_as_uint(v.y);
    u1 += 0x7fffu + ((u1 >> 16) & 1u);
    return __builtin_amdgcn_perm(u1, u0, 0x07060302);
}
__device__ __forceinline__ uint4v combine4(uint4v c00, uint4v c10, uint4v c01, uint4v c11,
                                           float w00, float w10, float w01, float w11) {
    f32x2 W00 = {w00, w00}, W10 = {w10, w10}, W01 = {w01, w01}, W11 = {w11, w11};
    uint4v r;
#pragma unroll
    for (int j = 0; j < 4; ++j) {
        f32x2 s = W00 * bf2x2(c00[j]) + W10 * bf2x2(c10[j])
                + W01 * bf2x2(c01[j]) + W11 * bf2x2(c11[j]);
        r[j] = pack_bf2(s);
    }
    return r;
}

// ---------------------------------------------------------------------------
// Fused prep: blocks 0..1023 transpose x NCHW f32 -> NHWC bf16;
// blocks 1024..1167 pack weight into MFMA B fragments.
// ---------------------------------------------------------------------------
__global__ __launch_bounds__(256) void dcl_prep(const float* __restrict__ x,
                                                const float* __restrict__ wgt,
                                                unsigned short* __restrict__ xt,
                                                unsigned short* __restrict__ wtb) {
    if (blockIdx.x < 1024) {
        __shared__ float tile[64][65];
        int chunk = blockIdx.x;
        int b = chunk >> 8;
        int hw0 = (chunk & 255) * 64;
        int tid = threadIdx.x;          // 0..255
        int tx = tid & 63;
        int ty = tid >> 6;
        const float* xb = x + (size_t)b * CH * HW;
#pragma unroll
        for (int c = ty; c < 64; c += 4)
            tile[c][tx] = xb[(size_t)c * HW + hw0 + tx];
        __syncthreads();
        unsigned short* xtb = xt + ((size_t)b << 20);
        int c4 = (tid & 15) * 4;
        int p0 = tid >> 4;              // 0..15
#pragma unroll
        for (int it = 0; it < 4; ++it) {
            int pxl = p0 + it * 16;
            ushort4v v = { f2bf(tile[c4 + 0][pxl]), f2bf(tile[c4 + 1][pxl]),
                           f2bf(tile[c4 + 2][pxl]), f2bf(tile[c4 + 3][pxl]) };
            *(ushort4v*)(xtb + (size_t)(hw0 + pxl) * CH + c4) = v;
        }
    } else {
        // wpack: lane l of frag (ks,nt) holds B[k][n], k=ks*32+(l>>4)*8+j,
        // n=nt*16+(l&15), k=t*64+c.  addr: wtb[((ks*4+nt)*64+l)*8+j]
        int idx = (blockIdx.x - 1024) * 256 + threadIdx.x;   // 0..36863
        int j  = idx & 7;
        int l  = (idx >> 3) & 63;
        int nt = (idx >> 9) & 3;
        int ks = idx >> 11;
        int k = ks * 32 + ((l >> 4) * 8) + j;
        int n = nt * 16 + (l & 15);
        int c = k & 63;
        int t = k >> 6;
        wtb[idx] = f2bf(wgt[(n * CH + c) * KK + t]);
    }
}

// ---------------------------------------------------------------------------
// Main: block = 8 waves = 512 thr over a 16x4 px tile, TAP-SPLIT:
// waves 0-3 (group 0, one px-row each) do taps 0-4; waves 4-7 (group 1,
// same px-rows) do taps 5-8. Grid 1024 -> 4 blocks/CU = 32 waves/CU =
// 8 waves/SIMD (2x R8) — first round combining full occupancy + VGPR depth
// + B-off-VMEM. B streamed per-iter for both groups through 4 x 8 KB
// double-buffered LDS. Epilogue sums the two groups' partial C via LDS.
// ---------------------------------------------------------------------------
#define SMEM_INTS 8320               // 33280 B: staging 4*2048 ints; epi 8*1040

__global__ __launch_bounds__(512, 8) void dcl_main(
        const unsigned short* __restrict__ xt,   // [b][h][w][c] bf16
        const float* __restrict__ offset,
        const unsigned short* __restrict__ wtb,  // packed B fragments (72 KB)
        const float* __restrict__ bias,
        float* __restrict__ out) {
    __shared__ __align__(16) int smem[SMEM_INTS];
    int tid = threadIdx.x;          // 0..511
    int lane = tid & 63;
    int wave = tid >> 6;            // 0..7
    int group = wave >> 2;          // 0: taps 0-4, 1: taps 5-8
    int r = wave & 3;               // px row within tile

    // 16x4 pixel tile: 8 x-tiles, 32 y-tiles per image
    int b  = blockIdx.x >> 8;
    int t8 = blockIdx.x & 255;
    int x0 = (t8 & 7) << 4;
    int y0 = (t8 >> 3) << 2;
    int m = lane & 15;
    int quad = lane >> 4;
    int qoff = quad * 16;
    int y = y0 + r;                 // this wave's pixel row
    int pm = x0 + m;                // this lane's pixel x

    const char* xtb = (const char*)xt;
    const float* ob = offset + (((size_t)(b * 18)) << 14) + (y << 7) + pm;
    float pxf = (float)pm;
    float pyf = (float)y;
    int t0 = group ? 5 : 0;

    const uint4v* bsrc = (const uint4v*)wtb;   // 512 uint4v per tap

    // ---- prologue: stage iter-0 B for both groups; load tap t0 offsets ----
    {
        uint4v* d0 = (uint4v*)(smem);            // g0, parity 0
        uint4v* d1 = (uint4v*)(smem + 2 * 2048); // g1, parity 0
        d0[tid] = bsrc[0 * 512 + tid];
        d1[tid] = bsrc[5 * 512 + tid];
    }
    float ox_c = ob[(size_t)(2 * t0) << 14];
    float oy_c = ob[(size_t)(2 * t0 + 1) << 14];

    f32x4 acc[4];
#pragma unroll
    for (int i = 0; i < 4; ++i) acc[i] = (f32x4)(0.f);

    __syncthreads();

#pragma unroll 1
    for (int i = 0; i < 5; ++i) {
        // ---- issue next-iter B loads + next-tap offset loads ----
        uint4v r0, r1;
        float ox_n = 0.f, oy_n = 0.f;
        if (i < 4) {
            r0 = bsrc[(i + 1) * 512 + tid];          // g0 tap i+1
            int tg1 = (6 + i < 9) ? (6 + i) : 8;     // g1 tap (dup-safe at i=3)
            r1 = bsrc[tg1 * 512 + tid];
            int tn = t0 + i + 1;
            if (tn > 8) tn = 8;
            ox_n = ob[(size_t)(2 * tn) << 14];
            oy_n = ob[(size_t)(2 * tn + 1) << 14];
        }

        // ---- gather + combine + MFMA for this group's tap ----
        if (group == 0 || i < 4) {                   // wave-uniform
            float fx = pxf + ox_c;
            float fy = pyf + oy_c;
            float x0f = floorf(fx), y0f = floorf(fy);
            float wx1 = fx - x0f, wy1 = fy - y0f;
            float wx0 = 1.0f - wx1, wy0 = 1.0f - wy1;
            int ix0 = (int)x0f, iy0 = (int)y0f;
            int ix1 = ix0 + 1, iy1 = iy0 + 1;
            bool vx0 = (unsigned)ix0 < (unsigned)WW;
            bool vx1 = (unsigned)ix1 < (unsigned)WW;
            bool vy0 = (unsigned)iy0 < (unsigned)HH;
            bool vy1 = (unsigned)iy1 < (unsigned)HH;
            float w00 = (vx0 && vy0) ? wx0 * wy0 : 0.0f;
            float w10 = (vx1 && vy0) ? wx1 * wy0 : 0.0f;
            float w01 = (vx0 && vy1) ? wx0 * wy1 : 0.0f;
            float w11 = (vx1 && vy1) ? wx1 * wy1 : 0.0f;
            int cx0 = min(max(ix0, 0), WW - 1), cx1 = min(max(ix1, 0), WW - 1);
            int cy0 = min(max(iy0, 0), HH - 1), cy1 = min(max(iy1, 0), HH - 1);
            int base = b << 14;
            int o00 = ((base + (cy0 << 7) + cx0) << 7) + qoff;   // 128 B/px
            int o10 = ((base + (cy0 << 7) + cx1) << 7) + qoff;
            int o01 = ((base + (cy1 << 7) + cx0) << 7) + qoff;
            int o11 = ((base + (cy1 << 7) + cx1) << 7) + qoff;

            uint4v c00a = *(const uint4v*)(xtb + o00);
            uint4v c10a = *(const uint4v*)(xtb + o10);
            uint4v c01a = *(const uint4v*)(xtb + o01);
            uint4v c11a = *(const uint4v*)(xtb + o11);
            uint4v c00b = *(const uint4v*)(xtb + o00 + 64);
            uint4v c10b = *(const uint4v*)(xtb + o10 + 64);
            uint4v c01b = *(const uint4v*)(xtb + o01 + 64);
            uint4v c11b = *(const uint4v*)(xtb + o11 + 64);
            uint4v ra = combine4(c00a, c10a, c01a, c11a, w00, w10, w01, w11);
            uint4v rb = combine4(c00b, c10b, c01b, c11b, w00, w10, w01, w11);
            short8 aa = __builtin_bit_cast(short8, ra);
            short8 ab = __builtin_bit_cast(short8, rb);

            const short8* bl = (const short8*)(smem + (group * 2 + (i & 1)) * 2048);
#pragma unroll
            for (int nt = 0; nt < 4; ++nt)
                acc[nt] = __builtin_amdgcn_mfma_f32_16x16x32_bf16(
                    aa, bl[nt * 64 + lane], acc[nt], 0, 0, 0);
#pragma unroll
            for (int nt = 0; nt < 4; ++nt)
                acc[nt] = __builtin_amdgcn_mfma_f32_16x16x32_bf16(
                    ab, bl[(4 + nt) * 64 + lane], acc[nt], 0, 0, 0);
        }

        // ---- commit next-iter B to the other parity ----
        if (i < 4) {
            int p1 = (i + 1) & 1;
            ((uint4v*)(smem + (0 + p1) * 2048))[tid] = r0;
            ((uint4v*)(smem + (2 + p1) * 2048))[tid] = r1;
        }
        ox_c = ox_n;
        oy_c = oy_n;
        __syncthreads();
    }

    // ---- epilogue: per-wave partial C -> LDS slice, sum groups, store ----
    float* o_w = (float*)smem + wave * 1040;    // [px_x][o], stride 65
#pragma unroll
    for (int nt = 0; nt < 4; ++nt)
#pragma unroll
        for (int reg = 0; reg < 4; ++reg)
            o_w[(quad * 4 + reg) * 65 + nt * 16 + m] = acc[nt][reg];
    __syncthreads();

    const float* os = (const float*)smem;
#pragma unroll
    for (int j = tid; j < 64 * 64; j += 512) {
        int o = j >> 6;                  // wave-uniform per iteration
        int p = j & 63;
        int row = p >> 4, xx = p & 15;
        float v = os[row * 1040 + xx * 65 + o]
                + os[(row + 4) * 1040 + xx * 65 + o] + bias[o];
        out[(((size_t)(b * OH + o)) << 14) + ((y0 + row) << 7) + x0 + xx] = v;
    }
}

extern "C" void kernel_launch(void* const* d_in, const int* in_sizes, int n_in,
                              void* d_out, int out_size, void* d_ws, size_t ws_size,
                              hipStream_t stream) {
    const float* x      = (const float*)d_in[0];
    const float* offset = (const float*)d_in[1];
    const float* weight = (const float*)d_in[2];
    const float* bias   = (const float*)d_in[3];
    float* out = (float*)d_out;

    unsigned short* xt  = (unsigned short*)d_ws;                           // 8.39 MB
    unsigned short* wtb = (unsigned short*)((char*)d_ws + (size_t)BH * HW * CH * 2);

    dcl_prep<<<1024 + 144, 256, 0, stream>>>(x, weight, xt, wtb);
    dcl_main<<<(BH * HW) / 64, 512, 0, stream>>>(xt, offset, wtb, bias, out);
}

// Round 10
// 102.495 us; speedup vs baseline: 1.4446x; 1.4446x over previous
//
#include <hip/hip_runtime.h>
#include <cstddef>

#define BH 4
#define CH 64
#define OH 64
#define HH 128
#define WW 128
#define KK 9
#define HW (HH * WW)     // 16384

#define HX 4             // x halo
#define HY 4             // y halo
#define TW 25            // tile cols  (16 + 2*4 + 1)
#define TH 13            // tile rows  (4 + 2*4 + 1)
#define NREC (TW * TH)   // 325 pixel records in LDS
#define NCHUNK (NREC * 8)   // 2600 16-B staging chunks

typedef __attribute__((ext_vector_type(8))) short short8;       // 8 bf16
typedef __attribute__((ext_vector_type(4))) float f32x4;        // MFMA acc
typedef __attribute__((ext_vector_type(2))) float f32x2;
typedef __attribute__((ext_vector_type(4))) unsigned int uint4v;
typedef __attribute__((ext_vector_type(4))) unsigned short ushort4v;

__device__ __forceinline__ unsigned short f2bf(float f) {
    unsigned u = __float_as_uint(f);
    u += 0x7fffu + ((u >> 16) & 1u);   // RNE
    return (unsigned short)(u >> 16);
}
__device__ __forceinline__ f32x2 bf2x2(unsigned d) {
    f32x2 r;
    r.x = __uint_as_float(d << 16);
    r.y = __uint_as_float(d & 0xffff0000u);
    return r;
}
__device__ __forceinline__ unsigned pack_bf2(f32x2 v) {
    unsigned u0 = __float_as_uint(v.x);
    u0 += 0x7fffu + ((u0 >> 16) & 1u);
    unsigned u1 = __float_as_uint(v.y);
    u1 += 0x7fffu + ((u1 >> 16) & 1u);
    return __builtin_amdgcn_perm(u1, u0, 0x07060302);
}
__device__ __forceinline__ uint4v combine4(uint4v c00, uint4v c10, uint4v c01, uint4v c11,
                                           float w00, float w10, float w01, float w11) {
    f32x2 W00 = {w00, w00}, W10 = {w10, w10}, W01 = {w01, w01}, W11 = {w11, w11};
    uint4v r;
#pragma unroll
    for (int j = 0; j < 4; ++j) {
        f32x2 s = W00 * bf2x2(c00[j]) + W10 * bf2x2(c10[j])
                + W01 * bf2x2(c01[j]) + W11 * bf2x2(c11[j]);
        r[j] = pack_bf2(s);
    }
    return r;
}

// ---------------------------------------------------------------------------
// Fused prep: blocks 0..1023 transpose x NCHW f32 -> NHWC bf16;
// blocks 1024..1167 pack weight into MFMA B fragments.
// ---------------------------------------------------------------------------
__global__ __launch_bounds__(256) void dcl_prep(const float* __restrict__ x,
                                                const float* __restrict__ wgt,
                                                unsigned short* __restrict__ xt,
                                                unsigned short* __restrict__ wtb) {
    if (blockIdx.x < 1024) {
        __shared__ float tile[64][65];
        int chunk = blockIdx.x;
        int b = chunk >> 8;
        int hw0 = (chunk & 255) * 64;
        int tid = threadIdx.x;          // 0..255
        int tx = tid & 63;
        int ty = tid >> 6;
        const float* xb = x + (size_t)b * CH * HW;
#pragma unroll
        for (int c = ty; c < 64; c += 4)
            tile[c][tx] = xb[(size_t)c * HW + hw0 + tx];
        __syncthreads();
        unsigned short* xtb = xt + ((size_t)b << 20);
        int c4 = (tid & 15) * 4;
        int p0 = tid >> 4;              // 0..15
#pragma unroll
        for (int it = 0; it < 4; ++it) {
            int pxl = p0 + it * 16;
            ushort4v v = { f2bf(tile[c4 + 0][pxl]), f2bf(tile[c4 + 1][pxl]),
                           f2bf(tile[c4 + 2][pxl]), f2bf(tile[c4 + 3][pxl]) };
            *(ushort4v*)(xtb + (size_t)(hw0 + pxl) * CH + c4) = v;
        }
    } else {
        // wpack: lane l of frag (ks,nt) holds B[k][n], k=ks*32+(l>>4)*8+j,
        // n=nt*16+(l&15), k=t*64+c.  addr: wtb[((ks*4+nt)*64+l)*8+j]
        int idx = (blockIdx.x - 1024) * 256 + threadIdx.x;   // 0..36863
        int j  = idx & 7;
        int l  = (idx >> 3) & 63;
        int nt = (idx >> 9) & 3;
        int ks = idx >> 11;
        int k = ks * 32 + ((l >> 4) * 8) + j;
        int n = nt * 16 + (l & 15);
        int c = k & 63;
        int t = k >> 6;
        wtb[idx] = f2bf(wgt[(n * CH + c) * KK + t]);
    }
}

// ---------------------------------------------------------------------------
// Main: block = 4 waves over a 16x4 px tile. The pixel tile + halo (25x13
// records, 41.6 KB) is staged to LDS ONCE with coalesced loads; all bilinear
// corner gathers become ds_read_b128 from LDS (swizzled: record p rotated by
// (p&7)*16B so scattered reads are <=2-way bank conflicts = free). This cuts
// the TA scatter-request count ~10x (the R5-R8 43us invariant). Out-of-halo
// offsets (P~6e-5) fall back to exec-masked global gathers. B fragments read
// from global (L2-hot, coalesced). ONE barrier before the tap loop.
// ---------------------------------------------------------------------------
__global__ __launch_bounds__(256, 4) void dcl_main(
        const unsigned short* __restrict__ xt,   // [b][h][w][c] bf16
        const float* __restrict__ offset,
        const unsigned short* __restrict__ wtb,  // packed B fragments (72 KB)
        const float* __restrict__ bias,
        float* __restrict__ out) {
    __shared__ __align__(16) int smem[NREC * 32];   // 41600 B
    int tid = threadIdx.x;          // 0..255
    int lane = tid & 63;
    int wave = tid >> 6;            // 0..3

    // 16x4 pixel tile: 8 x-tiles, 32 y-tiles per image
    int b  = blockIdx.x >> 8;
    int t8 = blockIdx.x & 255;
    int x0 = (t8 & 7) << 4;
    int y0 = (t8 >> 3) << 2;
    int m = lane & 15;
    int quad = lane >> 4;
    int qoff = quad * 16;
    int y = y0 + wave;              // this wave's pixel row
    int pm = x0 + m;                // this lane's pixel x

    const char* xtb = (const char*)xt;
    const char* xim = xtb + (((size_t)b << 14) << 7);   // image base (bytes)
    const float* ob = offset + (((size_t)(b * 18)) << 14) + (y << 7) + pm;
    float pxf = (float)pm;
    float pyf = (float)y;

    // ---- preload all 18 offset values ----
    float oxv[9], oyv[9];
#pragma unroll
    for (int t = 0; t < 9; ++t) {
        oxv[t] = ob[(size_t)(2 * t) << 14];
        oyv[t] = ob[(size_t)(2 * t + 1) << 14];
    }

    // ---- stage pixel tile + halo into LDS (coalesced, swizzled) ----
    uint4v* sv = (uint4v*)smem;
#pragma unroll
    for (int i = 0; i < 11; ++i) {
        int id = tid + i * 256;
        if (id < NCHUNK) {
            int p = id >> 3, sub = id & 7;
            int r = p / TW, col = p - r * TW;
            int sy = min(max(y0 - HY + r, 0), HH - 1);
            int sx = min(max(x0 - HX + col, 0), WW - 1);
            uint4v v = *(const uint4v*)(xim + (((sy << 7) + sx) << 7) + (sub << 4));
            sv[p * 8 + ((sub + (p & 7)) & 7)] = v;
        }
    }

    f32x4 acc[4];
#pragma unroll
    for (int i = 0; i < 4; ++i) acc[i] = (f32x4)(0.f);

    const short8* bfrags = (const short8*)wtb;

    __syncthreads();                // tile visible; only pre-epilogue barrier

    // ---- 9 taps, fully unrolled, barrier-free ----
#pragma unroll
    for (int t = 0; t < 9; ++t) {
        float fx = pxf + oxv[t];
        float fy = pyf + oyv[t];
        float x0f = floorf(fx), y0f = floorf(fy);
        float wx1 = fx - x0f, wy1 = fy - y0f;
        float wx0 = 1.0f - wx1, wy0 = 1.0f - wy1;
        int ix0 = (int)x0f, iy0 = (int)y0f;
        int ix1 = ix0 + 1, iy1 = iy0 + 1;
        bool vx0 = (unsigned)ix0 < (unsigned)WW;
        bool vx1 = (unsigned)ix1 < (unsigned)WW;
        bool vy0 = (unsigned)iy0 < (unsigned)HH;
        bool vy1 = (unsigned)iy1 < (unsigned)HH;
        float w00 = (vx0 && vy0) ? wx0 * wy0 : 0.0f;
        float w10 = (vx1 && vy0) ? wx1 * wy0 : 0.0f;
        float w01 = (vx0 && vy1) ? wx0 * wy1 : 0.0f;
        float w11 = (vx1 && vy1) ? wx1 * wy1 : 0.0f;
        int cx0 = min(max(ix0, 0), WW - 1), cx1 = min(max(ix1, 0), WW - 1);
        int cy0 = min(max(iy0, 0), HH - 1), cy1 = min(max(iy1, 0), HH - 1);

        // tile-local coords (image-clamped coords are consistent with the
        // clamped staging, so edge clamping never triggers the fallback)
        int lc0 = cx0 - x0 + HX, lc1 = cx1 - x0 + HX;
        int lr0 = cy0 - y0 + HY, lr1 = cy1 - y0 + HY;
        bool oof = ((unsigned)lc0 > (TW - 1)) | ((unsigned)lc1 > (TW - 1)) |
                   ((unsigned)lr0 > (TH - 1)) | ((unsigned)lr1 > (TH - 1));
        int sc0 = min(max(lc0, 0), TW - 1), sc1 = min(max(lc1, 0), TW - 1);
        int sr0 = min(max(lr0, 0), TH - 1), sr1 = min(max(lr1, 0), TH - 1);
        int p00 = sr0 * TW + sc0, p10 = sr0 * TW + sc1;
        int p01 = sr1 * TW + sc0, p11 = sr1 * TW + sc1;

        uint4v c00a = sv[p00 * 8 + ((quad + (p00 & 7)) & 7)];
        uint4v c00b = sv[p00 * 8 + ((quad + 4 + (p00 & 7)) & 7)];
        uint4v c10a = sv[p10 * 8 + ((quad + (p10 & 7)) & 7)];
        uint4v c10b = sv[p10 * 8 + ((quad + 4 + (p10 & 7)) & 7)];
        uint4v c01a = sv[p01 * 8 + ((quad + (p01 & 7)) & 7)];
        uint4v c01b = sv[p01 * 8 + ((quad + 4 + (p01 & 7)) & 7)];
        uint4v c11a = sv[p11 * 8 + ((quad + (p11 & 7)) & 7)];
        uint4v c11b = sv[p11 * 8 + ((quad + 4 + (p11 & 7)) & 7)];

        if (__builtin_expect(oof, 0)) {   // rare: genuinely large offsets
            int base = b << 14;
            int o00 = ((base + (cy0 << 7) + cx0) << 7) + qoff;
            int o10 = ((base + (cy0 << 7) + cx1) << 7) + qoff;
            int o01 = ((base + (cy1 << 7) + cx0) << 7) + qoff;
            int o11 = ((base + (cy1 << 7) + cx1) << 7) + qoff;
            c00a = *(const uint4v*)(xtb + o00);
            c00b = *(const uint4v*)(xtb + o00 + 64);
            c10a = *(const uint4v*)(xtb + o10);
            c10b = *(const uint4v*)(xtb + o10 + 64);
            c01a = *(const uint4v*)(xtb + o01);
            c01b = *(const uint4v*)(xtb + o01 + 64);
            c11a = *(const uint4v*)(xtb + o11);
            c11b = *(const uint4v*)(xtb + o11 + 64);
        }

        uint4v ra = combine4(c00a, c10a, c01a, c11a, w00, w10, w01, w11);
        uint4v rb = combine4(c00b, c10b, c01b, c11b, w00, w10, w01, w11);
        short8 aa = __builtin_bit_cast(short8, ra);
        short8 ab = __builtin_bit_cast(short8, rb);

        int ks = 2 * t;
#pragma unroll
        for (int nt = 0; nt < 4; ++nt)
            acc[nt] = __builtin_amdgcn_mfma_f32_16x16x32_bf16(
                aa, bfrags[(ks * 4 + nt) * 64 + lane], acc[nt], 0, 0, 0);
#pragma unroll
        for (int nt = 0; nt < 4; ++nt)
            acc[nt] = __builtin_amdgcn_mfma_f32_16x16x32_bf16(
                ab, bfrags[((ks + 1) * 4 + nt) * 64 + lane], acc[nt], 0, 0, 0);
    }

    // ---- epilogue: C tiles -> LDS (reuse tile area), coalesced store ----
    __syncthreads();
    float* o_w = (float*)smem + wave * 1040;    // [x_local][o], stride 65
#pragma unroll
    for (int nt = 0; nt < 4; ++nt)
#pragma unroll
        for (int reg = 0; reg < 4; ++reg)
            o_w[(quad * 4 + reg) * 65 + nt * 16 + m] = acc[nt][reg];
    __syncthreads();

    const float* os = (const float*)smem;
#pragma unroll
    for (int j = tid; j < 64 * 64; j += 256) {
        int o = j >> 6;                  // wave-uniform per iteration
        int p = j & 63;
        int row = p >> 4, xx = p & 15;
        float v = os[row * 1040 + xx * 65 + o] + bias[o];
        out[(((size_t)(b * OH + o)) << 14) + ((y0 + row) << 7) + x0 + xx] = v;
    }
}

extern "C" void kernel_launch(void* const* d_in, const int* in_sizes, int n_in,
                              void* d_out, int out_size, void* d_ws, size_t ws_size,
                              hipStream_t stream) {
    const float* x      = (const float*)d_in[0];
    const float* offset = (const float*)d_in[1];
    const float* weight = (const float*)d_in[2];
    const float* bias   = (const float*)d_in[3];
    float* out = (float*)d_out;

    unsigned short* xt  = (unsigned short*)d_ws;                           // 8.39 MB
    unsigned short* wtb = (unsigned short*)((char*)d_ws + (size_t)BH * HW * CH * 2);

    dcl_prep<<<1024 + 144, 256, 0, stream>>>(x, weight, xt, wtb);
    dcl_main<<<(BH * HW) / 64, 256, 0, stream>>>(xt, offset, wtb, bias, out);
}

// Round 11
// 101.097 us; speedup vs baseline: 1.4645x; 1.0138x over previous
//
#include <hip/hip_runtime.h>
#include <cstddef>

#define BH 4
#define CH 64
#define OH 64
#define HH 128
#define WW 128
#define KK 9
#define HW (HH * WW)     // 16384

#define HX 4             // x halo (symmetric)
#define HYT 4            // y halo above
#define TW 25            // tile cols  (16 + 2*4 + 1)
#define TH 12            // tile rows  (4 + 4 above + 4 below, asym: -4..+7)
#define NREC (TW * TH)   // 300 pixel records in LDS (38.4 KB -> 4 blocks/CU)
#define NCHUNK (NREC * 8)   // 2400 16-B staging chunks

typedef __attribute__((ext_vector_type(8))) short short8;       // 8 bf16
typedef __attribute__((ext_vector_type(4))) float f32x4;        // MFMA acc
typedef __attribute__((ext_vector_type(2))) float f32x2;
typedef __attribute__((ext_vector_type(4))) unsigned int uint4v;
typedef __attribute__((ext_vector_type(8))) unsigned short ushort8v;

__device__ __forceinline__ unsigned short f2bf(float f) {
    unsigned u = __float_as_uint(f);
    u += 0x7fffu + ((u >> 16) & 1u);   // RNE
    return (unsigned short)(u >> 16);
}
__device__ __forceinline__ f32x2 bf2x2(unsigned d) {
    f32x2 r;
    r.x = __uint_as_float(d << 16);
    r.y = __uint_as_float(d & 0xffff0000u);
    return r;
}
__device__ __forceinline__ unsigned pack_bf2(f32x2 v) {
    unsigned u0 = __float_as_uint(v.x);
    u0 += 0x7fffu + ((u0 >> 16) & 1u);
    unsigned u1 = __float_as_uint(v.y);
    u1 += 0x7fffu + ((u1 >> 16) & 1u);
    return __builtin_amdgcn_perm(u1, u0, 0x07060302);
}
__device__ __forceinline__ uint4v combine4(uint4v c00, uint4v c10, uint4v c01, uint4v c11,
                                           float w00, float w10, float w01, float w11) {
    f32x2 W00 = {w00, w00}, W10 = {w10, w10}, W01 = {w01, w01}, W11 = {w11, w11};
    uint4v r;
#pragma unroll
    for (int j = 0; j < 4; ++j) {
        f32x2 s = W00 * bf2x2(c00[j]) + W10 * bf2x2(c10[j])
                + W01 * bf2x2(c01[j]) + W11 * bf2x2(c11[j]);
        r[j] = pack_bf2(s);
    }
    return r;
}

// ---------------------------------------------------------------------------
// Fused prep: blocks 0..1023 transpose x NCHW f32 -> NHWC bf16 (float4 loads,
// ushort8 stores); blocks 1024..1167 pack weight into MFMA B fragments.
// ---------------------------------------------------------------------------
__global__ __launch_bounds__(256) void dcl_prep(const float* __restrict__ x,
                                                const float* __restrict__ wgt,
                                                unsigned short* __restrict__ xt,
                                                unsigned short* __restrict__ wtb) {
    if (blockIdx.x < 1024) {
        __shared__ float tile[64][68];   // stride 68: float4-aligned, bank-benign
        int chunk = blockIdx.x;
        int b = chunk >> 8;
        int hw0 = (chunk & 255) * 64;
        int tid = threadIdx.x;           // 0..255
        // load: 4 passes x (16 ch x 64 px) via float4
        int cg = tid >> 4;               // 0..15
        int tx4 = (tid & 15) * 4;        // 0,4,..,60
        const float* xb = x + (size_t)b * CH * HW + hw0;
#pragma unroll
        for (int pass = 0; pass < 4; ++pass) {
            int c = pass * 16 + cg;
            float4 v = *(const float4*)(xb + (size_t)c * HW + tx4);
            *(float4*)&tile[c][tx4] = v;
        }
        __syncthreads();
        // store: 2 passes x (32 px x 64 ch) via ushort8 (16 B)
        unsigned short* xtb = xt + ((size_t)b << 20) + (size_t)hw0 * CH;
        int c8 = (tid & 7) * 8;
        int p0 = tid >> 3;               // 0..31
#pragma unroll
        for (int it = 0; it < 2; ++it) {
            int pxl = p0 + it * 32;
            ushort8v v;
#pragma unroll
            for (int j = 0; j < 8; ++j) v[j] = f2bf(tile[c8 + j][pxl]);
            *(ushort8v*)(xtb + (size_t)pxl * CH + c8) = v;
        }
    } else {
        // wpack: lane l of frag (ks,nt) holds B[k][n], k=ks*32+(l>>4)*8+j,
        // n=nt*16+(l&15), k=t*64+c.  addr: wtb[((ks*4+nt)*64+l)*8+j]
        int idx = (blockIdx.x - 1024) * 256 + threadIdx.x;   // 0..36863
        int j  = idx & 7;
        int l  = (idx >> 3) & 63;
        int nt = (idx >> 9) & 3;
        int ks = idx >> 11;
        int k = ks * 32 + ((l >> 4) * 8) + j;
        int n = nt * 16 + (l & 15);
        int c = k & 63;
        int t = k >> 6;
        wtb[idx] = f2bf(wgt[(n * CH + c) * KK + t]);
    }
}

// ---------------------------------------------------------------------------
// Main: block = 4 waves over a 16x4 px tile. Pixel tile + asymmetric halo
// (25x12 records, 38.4 KB -> 4 blocks/CU) staged to LDS once (coalesced,
// swizzled: record p rotated by (p&7)*16B so scattered ds_read_b128 are
// <=2-way conflicts = free). Out-of-halo offsets (P~1e-5/lane-tap) fall back
// to exec-masked global gathers. B fragments from global (L2-hot, coalesced).
// ONE barrier before the tap loop.
// ---------------------------------------------------------------------------
__global__ __launch_bounds__(256, 4) void dcl_main(
        const unsigned short* __restrict__ xt,   // [b][h][w][c] bf16
        const float* __restrict__ offset,
        const unsigned short* __restrict__ wtb,  // packed B fragments (72 KB)
        const float* __restrict__ bias,
        float* __restrict__ out) {
    __shared__ __align__(16) int smem[NREC * 32];   // 38400 B
    int tid = threadIdx.x;          // 0..255
    int lane = tid & 63;
    int wave = tid >> 6;            // 0..3

    // 16x4 pixel tile: 8 x-tiles, 32 y-tiles per image
    int b  = blockIdx.x >> 8;
    int t8 = blockIdx.x & 255;
    int x0 = (t8 & 7) << 4;
    int y0 = (t8 >> 3) << 2;
    int m = lane & 15;
    int quad = lane >> 4;
    int qoff = quad * 16;
    int y = y0 + wave;              // this wave's pixel row
    int pm = x0 + m;                // this lane's pixel x

    const char* xtb = (const char*)xt;
    const char* xim = xtb + (((size_t)b << 14) << 7);   // image base (bytes)
    const float* ob = offset + (((size_t)(b * 18)) << 14) + (y << 7) + pm;
    float pxf = (float)pm;
    float pyf = (float)y;

    // ---- preload all 18 offset values ----
    float oxv[9], oyv[9];
#pragma unroll
    for (int t = 0; t < 9; ++t) {
        oxv[t] = ob[(size_t)(2 * t) << 14];
        oyv[t] = ob[(size_t)(2 * t + 1) << 14];
    }

    // ---- stage pixel tile + halo into LDS (coalesced, swizzled) ----
    uint4v* sv = (uint4v*)smem;
#pragma unroll
    for (int i = 0; i < 10; ++i) {
        int id = tid + i * 256;
        if (id < NCHUNK) {
            int p = id >> 3, sub = id & 7;
            int r = p / TW, col = p - r * TW;
            int sy = min(max(y0 - HYT + r, 0), HH - 1);
            int sx = min(max(x0 - HX + col, 0), WW - 1);
            uint4v v = *(const uint4v*)(xim + (((sy << 7) + sx) << 7) + (sub << 4));
            sv[p * 8 + ((sub + (p & 7)) & 7)] = v;
        }
    }

    f32x4 acc[4];
#pragma unroll
    for (int i = 0; i < 4; ++i) acc[i] = (f32x4)(0.f);

    const short8* bfrags = (const short8*)wtb;

    __syncthreads();                // tile visible; only pre-epilogue barrier

    // ---- 9 taps, fully unrolled, barrier-free ----
#pragma unroll
    for (int t = 0; t < 9; ++t) {
        float fx = pxf + oxv[t];
        float fy = pyf + oyv[t];
        float x0f = floorf(fx), y0f = floorf(fy);
        float wx1 = fx - x0f, wy1 = fy - y0f;
        float wx0 = 1.0f - wx1, wy0 = 1.0f - wy1;
        int ix0 = (int)x0f, iy0 = (int)y0f;
        int ix1 = ix0 + 1, iy1 = iy0 + 1;
        bool vx0 = (unsigned)ix0 < (unsigned)WW;
        bool vx1 = (unsigned)ix1 < (unsigned)WW;
        bool vy0 = (unsigned)iy0 < (unsigned)HH;
        bool vy1 = (unsigned)iy1 < (unsigned)HH;
        float w00 = (vx0 && vy0) ? wx0 * wy0 : 0.0f;
        float w10 = (vx1 && vy0) ? wx1 * wy0 : 0.0f;
        float w01 = (vx0 && vy1) ? wx0 * wy1 : 0.0f;
        float w11 = (vx1 && vy1) ? wx1 * wy1 : 0.0f;
        int cx0 = min(max(ix0, 0), WW - 1), cx1 = min(max(ix1, 0), WW - 1);
        int cy0 = min(max(iy0, 0), HH - 1), cy1 = min(max(iy1, 0), HH - 1);

        // tile-local coords (image-clamped coords match the clamped staging,
        // so image-edge clamping never triggers the fallback)
        int lc0 = cx0 - x0 + HX, lc1 = cx1 - x0 + HX;
        int lr0 = cy0 - y0 + HYT, lr1 = cy1 - y0 + HYT;
        bool oof = ((unsigned)lc0 > (TW - 1)) | ((unsigned)lc1 > (TW - 1)) |
                   ((unsigned)lr0 > (TH - 1)) | ((unsigned)lr1 > (TH - 1));
        int sc0 = min(max(lc0, 0), TW - 1), sc1 = min(max(lc1, 0), TW - 1);
        int sr0 = min(max(lr0, 0), TH - 1), sr1 = min(max(lr1, 0), TH - 1);
        int p00 = sr0 * TW + sc0, p10 = sr0 * TW + sc1;
        int p01 = sr1 * TW + sc0, p11 = sr1 * TW + sc1;

        uint4v c00a = sv[p00 * 8 + ((quad + (p00 & 7)) & 7)];
        uint4v c00b = sv[p00 * 8 + ((quad + 4 + (p00 & 7)) & 7)];
        uint4v c10a = sv[p10 * 8 + ((quad + (p10 & 7)) & 7)];
        uint4v c10b = sv[p10 * 8 + ((quad + 4 + (p10 & 7)) & 7)];
        uint4v c01a = sv[p01 * 8 + ((quad + (p01 & 7)) & 7)];
        uint4v c01b = sv[p01 * 8 + ((quad + 4 + (p01 & 7)) & 7)];
        uint4v c11a = sv[p11 * 8 + ((quad + (p11 & 7)) & 7)];
        uint4v c11b = sv[p11 * 8 + ((quad + 4 + (p11 & 7)) & 7)];

        if (__builtin_expect(oof, 0)) {   // rare: genuinely large offsets
            int base = b << 14;
            int o00 = ((base + (cy0 << 7) + cx0) << 7) + qoff;
            int o10 = ((base + (cy0 << 7) + cx1) << 7) + qoff;
            int o01 = ((base + (cy1 << 7) + cx0) << 7) + qoff;
            int o11 = ((base + (cy1 << 7) + cx1) << 7) + qoff;
            c00a = *(const uint4v*)(xtb + o00);
            c00b = *(const uint4v*)(xtb + o00 + 64);
            c10a = *(const uint4v*)(xtb + o10);
            c10b = *(const uint4v*)(xtb + o10 + 64);
            c01a = *(const uint4v*)(xtb + o01);
            c01b = *(const uint4v*)(xtb + o01 + 64);
            c11a = *(const uint4v*)(xtb + o11);
            c11b = *(const uint4v*)(xtb + o11 + 64);
        }

        uint4v ra = combine4(c00a, c10a, c01a, c11a, w00, w10, w01, w11);
        uint4v rb = combine4(c00b, c10b, c01b, c11b, w00, w10, w01, w11);
        short8 aa = __builtin_bit_cast(short8, ra);
        short8 ab = __builtin_bit_cast(short8, rb);

        int ks = 2 * t;
#pragma unroll
        for (int nt = 0; nt < 4; ++nt)
            acc[nt] = __builtin_amdgcn_mfma_f32_16x16x32_bf16(
                aa, bfrags[(ks * 4 + nt) * 64 + lane], acc[nt], 0, 0, 0);
#pragma unroll
        for (int nt = 0; nt < 4; ++nt)
            acc[nt] = __builtin_amdgcn_mfma_f32_16x16x32_bf16(
                ab, bfrags[((ks + 1) * 4 + nt) * 64 + lane], acc[nt], 0, 0, 0);
    }

    // ---- epilogue: C tiles -> LDS (reuse tile area), coalesced store ----
    __syncthreads();
    float* o_w = (float*)smem + wave * 1040;    // [x_local][o], stride 65
#pragma unroll
    for (int nt = 0; nt < 4; ++nt)
#pragma unroll
        for (int reg = 0; reg < 4; ++reg)
            o_w[(quad * 4 + reg) * 65 + nt * 16 + m] = acc[nt][reg];
    __syncthreads();

    const float* os = (const float*)smem;
#pragma unroll
    for (int j = tid; j < 64 * 64; j += 256) {
        int o = j >> 6;                  // wave-uniform per iteration
        int p = j & 63;
        int row = p >> 4, xx = p & 15;
        float v = os[row * 1040 + xx * 65 + o] + bias[o];
        out[(((size_t)(b * OH + o)) << 14) + ((y0 + row) << 7) + x0 + xx] = v;
    }
}

extern "C" void kernel_launch(void* const* d_in, const int* in_sizes, int n_in,
                              void* d_out, int out_size, void* d_ws, size_t ws_size,
                              hipStream_t stream) {
    const float* x      = (const float*)d_in[0];
    const float* offset = (const float*)d_in[1];
    const float* weight = (const float*)d_in[2];
    const float* bias   = (const float*)d_in[3];
    float* out = (float*)d_out;

    unsigned short* xt  = (unsigned short*)d_ws;                           // 8.39 MB
    unsigned short* wtb = (unsigned short*)((char*)d_ws + (size_t)BH * HW * CH * 2);

    dcl_prep<<<1024 + 144, 256, 0, stream>>>(x, weight, xt, wtb);
    dcl_main<<<(BH * HW) / 64, 256, 0, stream>>>(xt, offset, wtb, bias, out);
}